// Round 1
// baseline (1588.177 us; speedup 1.0000x reference)
//
#include <hip/hip_runtime.h>
#include <math.h>

#define NN 50000
#define NE 400000

__device__ __forceinline__ float sigmoidf_(float x) {
    return 1.0f / (1.0f + __expf(-x));
}
__device__ __forceinline__ float softplusf_(float x) {
    // stable: logaddexp(x, 0)
    return fmaxf(x, 0.0f) + log1pf(__expf(-fabsf(x)));
}

// Pack conv weights: Wpack[128][512] = [Wf_dst | Wf_src | Ws_dst | Ws_src],
// We[64][256] = [Wf_edge | Ws_edge], bcat[256] = [bf | bs]
__global__ void pack_weights(const float* __restrict__ Wf, const float* __restrict__ bf,
                             const float* __restrict__ Ws, const float* __restrict__ bs,
                             float* __restrict__ Wpack, float* __restrict__ We,
                             float* __restrict__ bcat) {
    int i = blockIdx.x * 256 + threadIdx.x;
    if (i < 128 * 512) {
        int k = i >> 9, c = i & 511;
        float w;
        if (c < 128)      w = Wf[k * 128 + c];
        else if (c < 256) w = Wf[(128 + k) * 128 + (c - 128)];
        else if (c < 384) w = Ws[k * 128 + (c - 256)];
        else              w = Ws[(128 + k) * 128 + (c - 384)];
        Wpack[i] = w;
    } else if (i < 128 * 512 + 64 * 256) {
        int j = i - 128 * 512;
        int k = j >> 8, c = j & 255;
        We[j] = (c < 128) ? Wf[(256 + k) * 128 + c] : Ws[(256 + k) * 128 + (c - 128)];
    } else if (i < 128 * 512 + 64 * 256 + 256) {
        int c = i - (128 * 512 + 64 * 256);
        bcat[c] = (c < 128) ? bf[c] : bs[c - 128];
    }
}

// fp32 reg-tiled GEMM: C[M,N] = A[M,K] @ B[K,N] (+ bias[N]). 64x64 tile, 4x4/thread.
__global__ __launch_bounds__(256) void gemm64(const float* __restrict__ A,
                                              const float* __restrict__ B,
                                              const float* __restrict__ bias,
                                              float* __restrict__ C,
                                              int M, int N, int K) {
    __shared__ float As[64][32];
    __shared__ float Bs[32][64];
    const int tid = threadIdx.x;
    const int tx = tid & 15, ty = tid >> 4;
    const int brow = blockIdx.x * 64;
    const int bcol = blockIdx.y * 64;
    float acc[4][4] = {};
    for (int k0 = 0; k0 < K; k0 += 32) {
        #pragma unroll
        for (int t = tid; t < 512; t += 256) {
            int r = t >> 3, c4 = t & 7;
            int gr = brow + r;
            float4 v = make_float4(0.f, 0.f, 0.f, 0.f);
            if (gr < M) v = *(const float4*)(A + (size_t)gr * K + k0 + c4 * 4);
            *(float4*)(&As[r][c4 * 4]) = v;
        }
        #pragma unroll
        for (int t = tid; t < 512; t += 256) {
            int r = t >> 4, c4 = t & 15;
            float4 v = *(const float4*)(B + (size_t)(k0 + r) * N + bcol + c4 * 4);
            *(float4*)(&Bs[r][c4 * 4]) = v;
        }
        __syncthreads();
        #pragma unroll
        for (int k = 0; k < 32; ++k) {
            float a0 = As[ty * 4 + 0][k];
            float a1 = As[ty * 4 + 1][k];
            float a2 = As[ty * 4 + 2][k];
            float a3 = As[ty * 4 + 3][k];
            float4 b = *(const float4*)(&Bs[k][tx * 4]);
            acc[0][0] = fmaf(a0, b.x, acc[0][0]); acc[0][1] = fmaf(a0, b.y, acc[0][1]);
            acc[0][2] = fmaf(a0, b.z, acc[0][2]); acc[0][3] = fmaf(a0, b.w, acc[0][3]);
            acc[1][0] = fmaf(a1, b.x, acc[1][0]); acc[1][1] = fmaf(a1, b.y, acc[1][1]);
            acc[1][2] = fmaf(a1, b.z, acc[1][2]); acc[1][3] = fmaf(a1, b.w, acc[1][3]);
            acc[2][0] = fmaf(a2, b.x, acc[2][0]); acc[2][1] = fmaf(a2, b.y, acc[2][1]);
            acc[2][2] = fmaf(a2, b.z, acc[2][2]); acc[2][3] = fmaf(a2, b.w, acc[2][3]);
            acc[3][0] = fmaf(a3, b.x, acc[3][0]); acc[3][1] = fmaf(a3, b.y, acc[3][1]);
            acc[3][2] = fmaf(a3, b.z, acc[3][2]); acc[3][3] = fmaf(a3, b.w, acc[3][3]);
        }
        __syncthreads();
    }
    float4 bv = make_float4(0.f, 0.f, 0.f, 0.f);
    if (bias) bv = *(const float4*)(bias + bcol + tx * 4);
    #pragma unroll
    for (int i = 0; i < 4; ++i) {
        int gr = brow + ty * 4 + i;
        if (gr < M) {
            float4 o;
            o.x = acc[i][0] + bv.x; o.y = acc[i][1] + bv.y;
            o.z = acc[i][2] + bv.z; o.w = acc[i][3] + bv.w;
            *(float4*)(C + (size_t)gr * N + bcol + tx * 4) = o;
        }
    }
}

// One wave per edge: gather P rows at dst/src, add Q (bias folded), gate*core,
// atomic accumulate into hacc[dst].
__global__ __launch_bounds__(256) void edge_kernel(const int* __restrict__ ei,
                                                   const float* __restrict__ P,
                                                   const float* __restrict__ Q,
                                                   float* __restrict__ hacc,
                                                   int e0, int ne) {
    int gid = blockIdx.x * 256 + threadIdx.x;
    int w = gid >> 6, lane = gid & 63;
    if (w >= ne) return;
    int e = e0 + w;
    int s = ei[e];        // edge_index[0] = src (x_j)
    int d = ei[NE + e];   // edge_index[1] = dst (x_i, aggregation target)
    const float2* Pd = (const float2*)(P + (size_t)d * 512);
    const float2* Ps = (const float2*)(P + (size_t)s * 512);
    const float2* Qe = (const float2*)(Q + (size_t)(e - e0) * 256);
    float2 af = Pd[lane];        // Af[dst]  cols 0..127
    float2 bf = Ps[64 + lane];   // Bf[src]  cols 128..255
    float2 as = Pd[128 + lane];  // As[dst]  cols 256..383
    float2 bs = Ps[192 + lane];  // Bs[src]  cols 384..511
    float2 qf = Qe[lane];        // Ef + bf
    float2 qs = Qe[64 + lane];   // Es + bs
    float gf0 = af.x + bf.x + qf.x;
    float gf1 = af.y + bf.y + qf.y;
    float gs0 = as.x + bs.x + qs.x;
    float gs1 = as.y + bs.y + qs.y;
    float m0 = sigmoidf_(gf0) * softplusf_(gs0);
    float m1 = sigmoidf_(gf1) * softplusf_(gs1);
    float* hp = hacc + (size_t)d * 128 + 2 * lane;
    atomicAdd(hp, m0);
    atomicAdd(hp + 1, m1);
}

__global__ void relu_copy(float* __restrict__ h1, float* __restrict__ h2, int n) {
    int i = blockIdx.x * 256 + threadIdx.x;
    if (i < n) {
        float v = fmaxf(h1[i], 0.0f);
        h1[i] = v;
        h2[i] = v;
    }
}

// out[n] = dot(h[n,:], Wfc) + bfc ; one wave per node
__global__ __launch_bounds__(256) void final_fc(const float* __restrict__ h,
                                                const float* __restrict__ W,
                                                const float* __restrict__ b,
                                                float* __restrict__ out) {
    int gid = blockIdx.x * 256 + threadIdx.x;
    int n = gid >> 6, lane = gid & 63;
    if (n >= NN) return;
    const float2* hp = (const float2*)(h + (size_t)n * 128);
    const float2* wp = (const float2*)W;
    float2 hv = hp[lane], wv = wp[lane];
    float p = hv.x * wv.x + hv.y * wv.y;
    #pragma unroll
    for (int off = 32; off > 0; off >>= 1) p += __shfl_down(p, off);
    if (lane == 0) out[n] = p + b[0];
}

extern "C" void kernel_launch(void* const* d_in, const int* in_sizes, int n_in,
                              void* d_out, int out_size, void* d_ws, size_t ws_size,
                              hipStream_t stream) {
    const float* x   = (const float*)d_in[0];
    const int*   ei  = (const int*)d_in[1];
    const float* ea  = (const float*)d_in[2];
    const float* Wf1 = (const float*)d_in[3];
    const float* bf1 = (const float*)d_in[4];
    const float* Ws1 = (const float*)d_in[5];
    const float* bs1 = (const float*)d_in[6];
    const float* Wf2 = (const float*)d_in[7];
    const float* bf2 = (const float*)d_in[8];
    const float* Ws2 = (const float*)d_in[9];
    const float* bs2 = (const float*)d_in[10];
    const float* Wfc = (const float*)d_in[11];
    const float* bfc = (const float*)d_in[12];
    float* out = (float*)d_out;

    float* ws = (float*)d_ws;
    float* h1    = ws;                         // NN*128
    float* h2    = h1 + (size_t)NN * 128;      // NN*128
    float* P     = h2 + (size_t)NN * 128;      // NN*512
    float* Wpack = P + (size_t)NN * 512;       // 128*512
    float* We    = Wpack + 128 * 512;          // 64*256
    float* bcat  = We + 64 * 256;              // 256
    float* Qc    = bcat + 256;                 // CH*256

    size_t base_floats = (size_t)(Qc - ws);
    long availE = ((long)(ws_size / 4) - (long)base_floats) / 256;
    long CHl = availE < 32768 ? availE : 32768;
    if (CHl < 64) CHl = 64;
    int CH = (int)(CHl & ~63L);

    hipMemcpyAsync(h1, x, (size_t)NN * 128 * 4, hipMemcpyDeviceToDevice, stream);

    for (int conv = 0; conv < 2; ++conv) {
        const float* Wf  = conv ? Wf2 : Wf1;
        const float* bf  = conv ? bf2 : bf1;
        const float* Wss = conv ? Ws2 : Ws1;
        const float* bs  = conv ? bs2 : bs1;
        const float* hin = conv ? h1 : x;
        float* hacc = conv ? h2 : h1;

        pack_weights<<<(128 * 512 + 64 * 256 + 256 + 255) / 256, 256, 0, stream>>>(
            Wf, bf, Wss, bs, Wpack, We, bcat);
        gemm64<<<dim3((NN + 63) / 64, 512 / 64), 256, 0, stream>>>(
            hin, Wpack, nullptr, P, NN, 512, 128);
        for (int e0 = 0; e0 < NE; e0 += CH) {
            int ne = (NE - e0 < CH) ? (NE - e0) : CH;
            gemm64<<<dim3((ne + 63) / 64, 256 / 64), 256, 0, stream>>>(
                ea + (size_t)e0 * 64, We, bcat, Qc, ne, 256, 64);
            edge_kernel<<<((ne * 64) + 255) / 256, 256, 0, stream>>>(
                ei, P, Qc, hacc, e0, ne);
        }
        if (conv == 0) {
            relu_copy<<<(NN * 128 + 255) / 256, 256, 0, stream>>>(h1, h2, NN * 128);
        }
    }
    final_fc<<<((NN * 64) + 255) / 256, 256, 0, stream>>>(h2, Wfc, bfc, out);
}

// Round 2
// 1450.260 us; speedup vs baseline: 1.0951x; 1.0951x over previous
//
#include <hip/hip_runtime.h>
#include <math.h>

#define NN 50000
#define NE 400000

typedef __attribute__((ext_vector_type(8))) short bf16x8;
typedef __attribute__((ext_vector_type(4))) float f32x4;

__device__ __forceinline__ unsigned short f2bf(float f) {
    unsigned int u = __float_as_uint(f);
    u += 0x7FFF + ((u >> 16) & 1);   // RNE
    return (unsigned short)(u >> 16);
}
__device__ __forceinline__ float2 upk(unsigned int w) {
    float2 r;
    r.x = __uint_as_float(w << 16);
    r.y = __uint_as_float(w & 0xFFFF0000u);
    return r;
}
__device__ __forceinline__ float sigmoidf_(float x) {
    return 1.0f / (1.0f + __expf(-x));
}
__device__ __forceinline__ float softplusf_(float x) {
    return fmaxf(x, 0.0f) + log1pf(__expf(-fabsf(x)));
}

// Pack one conv's weights transposed + bf16:
// WT[512][128]: cols 0-127 Wf(dst rows), 128-255 Wf(src rows), 256-383 Ws(dst), 384-511 Ws(src)
// WeT[256][64]: cols 0-127 Wf(edge rows), 128-255 Ws(edge rows)
// bcat[256] fp32 = [bf | bs]
__global__ void pack_weights(const float* __restrict__ Wf, const float* __restrict__ bf,
                             const float* __restrict__ Ws, const float* __restrict__ bs,
                             unsigned short* __restrict__ WT, unsigned short* __restrict__ WeT,
                             float* __restrict__ bcat) {
    int i = blockIdx.x * 256 + threadIdx.x;
    if (i < 512 * 128) {
        int c = i >> 7, k = i & 127;
        float w;
        if (c < 128)      w = Wf[k * 128 + c];
        else if (c < 256) w = Wf[(128 + k) * 128 + (c - 128)];
        else if (c < 384) w = Ws[k * 128 + (c - 256)];
        else              w = Ws[(128 + k) * 128 + (c - 384)];
        WT[i] = f2bf(w);
    } else if (i < 512 * 128 + 256 * 64) {
        int j = i - 512 * 128;
        int c = j >> 6, k = j & 63;
        float w = (c < 128) ? Wf[(256 + k) * 128 + c] : Ws[(256 + k) * 128 + (c - 128)];
        WeT[j] = f2bf(w);
    } else if (i < 512 * 128 + 256 * 64 + 256) {
        int c = i - (512 * 128 + 256 * 64);
        bcat[c] = (c < 128) ? bf[c] : bs[c - 128];
    }
}

// fp32 -> bf16 bulk convert, 8 elems/thread
__global__ void cvt_bf16(const float* __restrict__ in, unsigned short* __restrict__ out, int n8) {
    int i = blockIdx.x * 256 + threadIdx.x;
    if (i >= n8) return;
    const float4* p = (const float4*)in + (size_t)i * 2;
    float4 a = p[0], b = p[1];
    bf16x8 v;
    v[0] = (short)f2bf(a.x); v[1] = (short)f2bf(a.y);
    v[2] = (short)f2bf(a.z); v[3] = (short)f2bf(a.w);
    v[4] = (short)f2bf(b.x); v[5] = (short)f2bf(b.y);
    v[6] = (short)f2bf(b.z); v[7] = (short)f2bf(b.w);
    *((bf16x8*)out + i) = v;
}

// P[NN][512] (bf16) = h[NN][128] (fp32, converted on load) @ Wpack[128][512]
// block = 256 threads = 4 waves; each wave: 16 rows x 512 cols (32 mfma chunks)
__global__ __launch_bounds__(256) void node_gemm(const float* __restrict__ h,
                                                 const unsigned short* __restrict__ WT,
                                                 unsigned short* __restrict__ P) {
    int w = threadIdx.x >> 6, l = threadIdx.x & 63;
    int r0 = blockIdx.x * 64 + w * 16;
    int lrow = l & 15, lk = l >> 4;
    int arow = r0 + lrow;
    if (arow >= NN) arow = NN - 1;
    f32x4 acc[32];
    #pragma unroll
    for (int i = 0; i < 32; ++i) acc[i] = (f32x4){0.f, 0.f, 0.f, 0.f};
    #pragma unroll
    for (int ks = 0; ks < 4; ++ks) {
        int kb = ks * 32 + lk * 8;
        const float4* ap = (const float4*)(h + (size_t)arow * 128 + kb);
        float4 a0 = ap[0], a1 = ap[1];
        bf16x8 af;
        af[0] = (short)f2bf(a0.x); af[1] = (short)f2bf(a0.y);
        af[2] = (short)f2bf(a0.z); af[3] = (short)f2bf(a0.w);
        af[4] = (short)f2bf(a1.x); af[5] = (short)f2bf(a1.y);
        af[6] = (short)f2bf(a1.z); af[7] = (short)f2bf(a1.w);
        #pragma unroll
        for (int nc = 0; nc < 32; ++nc) {
            bf16x8 bfr = *(const bf16x8*)(WT + (size_t)(nc * 16 + lrow) * 128 + kb);
            acc[nc] = __builtin_amdgcn_mfma_f32_16x16x32_bf16(af, bfr, acc[nc], 0, 0, 0);
        }
    }
    int rb = r0 + lk * 4;
    #pragma unroll
    for (int nc = 0; nc < 32; ++nc) {
        int col = nc * 16 + lrow;
        #pragma unroll
        for (int r = 0; r < 4; ++r) {
            int row = rb + r;
            if (row < NN) P[(size_t)row * 512 + col] = f2bf(acc[nc][r]);
        }
    }
}

// Q[ne][256] (bf16) = ea_bf16[e0+..][64] @ We[64][256] + bcat
__global__ __launch_bounds__(256) void q_gemm(const unsigned short* __restrict__ ea,
                                              const unsigned short* __restrict__ WeT,
                                              const float* __restrict__ bcat,
                                              unsigned short* __restrict__ Q,
                                              int e0, int ne) {
    int w = threadIdx.x >> 6, l = threadIdx.x & 63;
    int r0 = blockIdx.x * 64 + w * 16;
    int lrow = l & 15, lk = l >> 4;
    int arow = r0 + lrow;
    if (arow >= ne) arow = ne - 1;
    f32x4 acc[16];
    #pragma unroll
    for (int i = 0; i < 16; ++i) acc[i] = (f32x4){0.f, 0.f, 0.f, 0.f};
    #pragma unroll
    for (int ks = 0; ks < 2; ++ks) {
        int kb = ks * 32 + lk * 8;
        bf16x8 af = *(const bf16x8*)(ea + (size_t)(e0 + arow) * 64 + kb);
        #pragma unroll
        for (int nc = 0; nc < 16; ++nc) {
            bf16x8 bfr = *(const bf16x8*)(WeT + (size_t)(nc * 16 + lrow) * 64 + kb);
            acc[nc] = __builtin_amdgcn_mfma_f32_16x16x32_bf16(af, bfr, acc[nc], 0, 0, 0);
        }
    }
    int rb = r0 + lk * 4;
    #pragma unroll
    for (int nc = 0; nc < 16; ++nc) {
        int col = nc * 16 + lrow;
        float bb = bcat[col];
        #pragma unroll
        for (int r = 0; r < 4; ++r) {
            int row = rb + r;
            if (row < ne) Q[(size_t)row * 256 + col] = f2bf(acc[nc][r] + bb);
        }
    }
}

// One wave per edge: gather bf16 P rows at dst/src, add bf16 Q (bias folded),
// sigmoid*softplus, fp32 atomicAdd into hacc[dst].
__global__ __launch_bounds__(256) void edge_kernel(const int* __restrict__ ei,
                                                   const unsigned short* __restrict__ P,
                                                   const unsigned short* __restrict__ Q,
                                                   float* __restrict__ hacc,
                                                   int e0, int ne) {
    int gid = blockIdx.x * 256 + threadIdx.x;
    int wv = gid >> 6, l = gid & 63;
    if (wv >= ne) return;
    int e = e0 + wv;
    int s = ei[e];        // source (x_j)
    int d = ei[NE + e];   // target (x_i)
    const unsigned int* Pd = (const unsigned int*)(P + (size_t)d * 512);
    const unsigned int* Ps = (const unsigned int*)(P + (size_t)s * 512);
    const unsigned int* Qe = (const unsigned int*)(Q + (size_t)wv * 256);
    float2 af = upk(Pd[l]);
    float2 bf_ = upk(Ps[64 + l]);
    float2 as = upk(Pd[128 + l]);
    float2 bs_ = upk(Ps[192 + l]);
    float2 qf = upk(Qe[l]);
    float2 qs = upk(Qe[64 + l]);
    float m0 = sigmoidf_(af.x + bf_.x + qf.x) * softplusf_(as.x + bs_.x + qs.x);
    float m1 = sigmoidf_(af.y + bf_.y + qf.y) * softplusf_(as.y + bs_.y + qs.y);
    float* hp = hacc + (size_t)d * 128 + 2 * l;
    atomicAdd(hp, m0);
    atomicAdd(hp + 1, m1);
}

__global__ void relu_copy(float* __restrict__ h1, float* __restrict__ h2, int n) {
    int i = blockIdx.x * 256 + threadIdx.x;
    if (i < n) {
        float v = fmaxf(h1[i], 0.0f);
        h1[i] = v;
        h2[i] = v;
    }
}

__global__ __launch_bounds__(256) void final_fc(const float* __restrict__ h,
                                                const float* __restrict__ W,
                                                const float* __restrict__ b,
                                                float* __restrict__ out) {
    int gid = blockIdx.x * 256 + threadIdx.x;
    int n = gid >> 6, lane = gid & 63;
    if (n >= NN) return;
    const float2* hp = (const float2*)(h + (size_t)n * 128);
    const float2* wp = (const float2*)W;
    float2 hv = hp[lane], wv = wp[lane];
    float p = hv.x * wv.x + hv.y * wv.y;
    #pragma unroll
    for (int off = 32; off > 0; off >>= 1) p += __shfl_down(p, off);
    if (lane == 0) out[n] = p + b[0];
}

extern "C" void kernel_launch(void* const* d_in, const int* in_sizes, int n_in,
                              void* d_out, int out_size, void* d_ws, size_t ws_size,
                              hipStream_t stream) {
    const float* x   = (const float*)d_in[0];
    const int*   ei  = (const int*)d_in[1];
    const float* ea  = (const float*)d_in[2];
    const float* Wf1 = (const float*)d_in[3];
    const float* bf1 = (const float*)d_in[4];
    const float* Ws1 = (const float*)d_in[5];
    const float* bs1 = (const float*)d_in[6];
    const float* Wf2 = (const float*)d_in[7];
    const float* bf2 = (const float*)d_in[8];
    const float* Ws2 = (const float*)d_in[9];
    const float* bs2 = (const float*)d_in[10];
    const float* Wfc = (const float*)d_in[11];
    const float* bfc = (const float*)d_in[12];
    float* out = (float*)d_out;

    // workspace layout (bytes, all 16B aligned)
    char* wsb = (char*)d_ws;
    float* h1 = (float*)wsb;                                   // NN*128 f32
    float* h2 = h1 + (size_t)NN * 128;                         // NN*128 f32
    unsigned short* P   = (unsigned short*)(h2 + (size_t)NN * 128); // NN*512 bf16
    unsigned short* eab = P + (size_t)NN * 512;                // NE*64 bf16
    unsigned short* WT  = eab + (size_t)NE * 64;               // 2 x 512*128 bf16
    unsigned short* WeT = WT + 2 * 512 * 128;                  // 2 x 256*64 bf16
    float* bcat = (float*)(WeT + 2 * 256 * 64);                // 2 x 256 f32
    unsigned short* Qc = (unsigned short*)((char*)bcat + 2 * 256 * 4); // CH*256 bf16

    size_t base_bytes = (size_t)((char*)Qc - wsb);
    long availE = ((long)ws_size - (long)base_bytes) / 512;    // 256 bf16 per edge
    long CHl = availE < 65536 ? availE : 65536;
    if (CHl < 64) CHl = 64;
    int CH = (int)(CHl & ~63L);

    hipMemcpyAsync(h1, x, (size_t)NN * 128 * 4, hipMemcpyDeviceToDevice, stream);
    cvt_bf16<<<(NE * 64 / 8 + 255) / 256, 256, 0, stream>>>(ea, eab, NE * 64 / 8);
    const int packN = 512 * 128 + 256 * 64 + 256;
    pack_weights<<<(packN + 255) / 256, 256, 0, stream>>>(Wf1, bf1, Ws1, bs1,
                                                          WT, WeT, bcat);
    pack_weights<<<(packN + 255) / 256, 256, 0, stream>>>(Wf2, bf2, Ws2, bs2,
                                                          WT + 512 * 128, WeT + 256 * 64, bcat + 256);

    for (int conv = 0; conv < 2; ++conv) {
        const float* hin = conv ? h1 : x;
        float* hacc = conv ? h2 : h1;
        node_gemm<<<(NN + 63) / 64, 256, 0, stream>>>(hin, WT + conv * 512 * 128, P);
        for (int e0 = 0; e0 < NE; e0 += CH) {
            int ne = (NE - e0 < CH) ? (NE - e0) : CH;
            q_gemm<<<(ne + 63) / 64, 256, 0, stream>>>(eab, WeT + conv * 256 * 64,
                                                       bcat + conv * 256, Qc, e0, ne);
            edge_kernel<<<((size_t)ne * 64 + 255) / 256, 256, 0, stream>>>(ei, P, Qc, hacc, e0, ne);
        }
        if (conv == 0) {
            relu_copy<<<(NN * 128 + 255) / 256, 256, 0, stream>>>(h1, h2, NN * 128);
        }
    }
    final_fc<<<((size_t)NN * 64 + 255) / 256, 256, 0, stream>>>(h2, Wfc, bfc, out);
}

// Round 3
// 620.975 us; speedup vs baseline: 2.5576x; 2.3355x over previous
//
#include <hip/hip_runtime.h>
#include <math.h>

#define NN 50000
#define NE 400000

typedef __attribute__((ext_vector_type(8))) short bf16x8;
typedef __attribute__((ext_vector_type(4))) float f32x4;
typedef unsigned short ushort_t;

__device__ __forceinline__ unsigned short f2bf(float f) {
    unsigned int u = __float_as_uint(f);
    u += 0x7FFF + ((u >> 16) & 1);   // RNE
    return (unsigned short)(u >> 16);
}
__device__ __forceinline__ float2 upk(unsigned int w) {
    float2 r;
    r.x = __uint_as_float(w << 16);
    r.y = __uint_as_float(w & 0xFFFF0000u);
    return r;
}
__device__ __forceinline__ float sigmoidf_(float x) {
    return 1.0f / (1.0f + __expf(-x));
}
__device__ __forceinline__ float softplusf_(float x) {
    return fmaxf(x, 0.0f) + log1pf(__expf(-fabsf(x)));
}

// WT[512][128]: row c = output col, contiguous k. cols 0-127 Wf(dst), 128-255 Wf(src),
// 256-383 Ws(dst), 384-511 Ws(src). WeT[256][64] same idea for edge part. bcat=[bf|bs].
__global__ void pack_weights(const float* __restrict__ Wf, const float* __restrict__ bf,
                             const float* __restrict__ Ws, const float* __restrict__ bs,
                             ushort_t* __restrict__ WT, ushort_t* __restrict__ WeT,
                             float* __restrict__ bcat) {
    int i = blockIdx.x * 256 + threadIdx.x;
    if (i < 512 * 128) {
        int c = i >> 7, k = i & 127;
        float w;
        if (c < 128)      w = Wf[k * 128 + c];
        else if (c < 256) w = Wf[(128 + k) * 128 + (c - 128)];
        else if (c < 384) w = Ws[k * 128 + (c - 256)];
        else              w = Ws[(128 + k) * 128 + (c - 384)];
        WT[i] = f2bf(w);
    } else if (i < 512 * 128 + 256 * 64) {
        int j = i - 512 * 128;
        int c = j >> 6, k = j & 63;
        float w = (c < 128) ? Wf[(256 + k) * 128 + c] : Ws[(256 + k) * 128 + (c - 128)];
        WeT[j] = f2bf(w);
    } else if (i < 512 * 128 + 256 * 64 + 256) {
        int c = i - (512 * 128 + 256 * 64);
        bcat[c] = (c < 128) ? bf[c] : bs[c - 128];
    }
}

// fp32 -> bf16 bulk convert, 8 elems/thread
__global__ void cvt_bf16(const float* __restrict__ in, ushort_t* __restrict__ out, int n8) {
    int i = blockIdx.x * 256 + threadIdx.x;
    if (i >= n8) return;
    const float4* p = (const float4*)in + (size_t)i * 2;
    float4 a = p[0], b = p[1];
    bf16x8 v;
    v[0] = (short)f2bf(a.x); v[1] = (short)f2bf(a.y);
    v[2] = (short)f2bf(a.z); v[3] = (short)f2bf(a.w);
    v[4] = (short)f2bf(b.x); v[5] = (short)f2bf(b.y);
    v[6] = (short)f2bf(b.z); v[7] = (short)f2bf(b.w);
    *((bf16x8*)out + i) = v;
}

// P[NN][512] (bf16) = hb[NN][128] (bf16) @ W. Grid (ceil(NN/64), 4); 4 waves/block.
// B slice (128 cols x 128 k) staged in LDS with +8 pad.
__global__ __launch_bounds__(256) void node_gemm(const ushort_t* __restrict__ hb,
                                                 const ushort_t* __restrict__ WT,
                                                 ushort_t* __restrict__ P) {
    __shared__ ushort_t Bs[128 * 136];
    const int tid = threadIdx.x;
    const int w = tid >> 6, l = tid & 63;
    const int by = blockIdx.y;
    const ushort_t* src = WT + (size_t)by * 128 * 128;
    #pragma unroll
    for (int j = 0; j < 8; ++j) {
        int cid = j * 256 + tid;            // 2048 chunks of 8 bf16
        int row = cid >> 4, off = (cid & 15) * 8;
        *(bf16x8*)(&Bs[row * 136 + off]) = *(const bf16x8*)(src + row * 128 + off);
    }
    __syncthreads();
    const int r0 = blockIdx.x * 64 + w * 16;
    const int lrow = l & 15, lk = l >> 4;
    int arow = r0 + lrow;
    if (arow >= NN) arow = NN - 1;
    f32x4 acc[8];
    #pragma unroll
    for (int i = 0; i < 8; ++i) acc[i] = (f32x4){0.f, 0.f, 0.f, 0.f};
    #pragma unroll
    for (int ks = 0; ks < 4; ++ks) {
        int kb = ks * 32 + lk * 8;
        bf16x8 af = *(const bf16x8*)(hb + (size_t)arow * 128 + kb);
        #pragma unroll
        for (int nc = 0; nc < 8; ++nc) {
            bf16x8 bfr = *(const bf16x8*)(&Bs[(nc * 16 + lrow) * 136 + kb]);
            acc[nc] = __builtin_amdgcn_mfma_f32_16x16x32_bf16(af, bfr, acc[nc], 0, 0, 0);
        }
    }
    const int rb = r0 + lk * 4;
    const int cb = by * 128;
    #pragma unroll
    for (int nc = 0; nc < 8; ++nc) {
        int col = cb + nc * 16 + lrow;
        #pragma unroll
        for (int r = 0; r < 4; ++r) {
            int row = rb + r;
            if (row < NN) P[(size_t)row * 512 + col] = f2bf(acc[nc][r]);
        }
    }
}

// Q[ne][256] (bf16) = eab[e0..][64] @ We + bcat. Grid (ceil(ne/64), 2).
__global__ __launch_bounds__(256) void q_gemm(const ushort_t* __restrict__ ea,
                                              const ushort_t* __restrict__ WeT,
                                              const float* __restrict__ bcat,
                                              ushort_t* __restrict__ Q,
                                              int e0, int ne) {
    __shared__ ushort_t Bs[128 * 72];
    const int tid = threadIdx.x;
    const int w = tid >> 6, l = tid & 63;
    const int by = blockIdx.y;
    const ushort_t* src = WeT + (size_t)by * 128 * 64;
    #pragma unroll
    for (int j = 0; j < 4; ++j) {
        int cid = j * 256 + tid;            // 1024 chunks of 8 bf16
        int row = cid >> 3, off = (cid & 7) * 8;
        *(bf16x8*)(&Bs[row * 72 + off]) = *(const bf16x8*)(src + row * 64 + off);
    }
    __syncthreads();
    const int r0 = blockIdx.x * 64 + w * 16;
    const int lrow = l & 15, lk = l >> 4;
    int arow = r0 + lrow;
    if (arow >= ne) arow = ne - 1;
    f32x4 acc[8];
    #pragma unroll
    for (int i = 0; i < 8; ++i) acc[i] = (f32x4){0.f, 0.f, 0.f, 0.f};
    #pragma unroll
    for (int ks = 0; ks < 2; ++ks) {
        int kb = ks * 32 + lk * 8;
        bf16x8 af = *(const bf16x8*)(ea + (size_t)(e0 + arow) * 64 + kb);
        #pragma unroll
        for (int nc = 0; nc < 8; ++nc) {
            bf16x8 bfr = *(const bf16x8*)(&Bs[(nc * 16 + lrow) * 72 + kb]);
            acc[nc] = __builtin_amdgcn_mfma_f32_16x16x32_bf16(af, bfr, acc[nc], 0, 0, 0);
        }
    }
    const int rb = r0 + lk * 4;
    const int cb = by * 128;
    #pragma unroll
    for (int nc = 0; nc < 8; ++nc) {
        int col = cb + nc * 16 + lrow;
        float bb = bcat[col];
        #pragma unroll
        for (int r = 0; r < 4; ++r) {
            int row = rb + r;
            if (row < ne) Q[(size_t)row * 256 + col] = f2bf(acc[nc][r] + bb);
        }
    }
}

// One wave per edge; packed bf16 atomic accumulate into hb[dst] (in place, P already built).
__global__ __launch_bounds__(256) void edge_kernel(const int* __restrict__ ei,
                                                   const ushort_t* __restrict__ P,
                                                   const ushort_t* __restrict__ Q,
                                                   ushort_t* __restrict__ hacc,
                                                   int e0, int ne) {
    int gid = blockIdx.x * 256 + threadIdx.x;
    int wv = gid >> 6, l = gid & 63;
    if (wv >= ne) return;
    int e = e0 + wv;
    int s = ei[e];        // source (x_j)
    int d = ei[NE + e];   // target (x_i)
    const unsigned int* Pd = (const unsigned int*)(P + (size_t)d * 512);
    const unsigned int* Ps = (const unsigned int*)(P + (size_t)s * 512);
    const unsigned int* Qe = (const unsigned int*)(Q + (size_t)wv * 256);
    float2 af = upk(Pd[l]);
    float2 bf_ = upk(Ps[64 + l]);
    float2 as = upk(Pd[128 + l]);
    float2 bs_ = upk(Ps[192 + l]);
    float2 qf = upk(Qe[l]);
    float2 qs = upk(Qe[64 + l]);
    float m0 = sigmoidf_(af.x + bf_.x + qf.x) * softplusf_(as.x + bs_.x + qs.x);
    float m1 = sigmoidf_(af.y + bf_.y + qf.y) * softplusf_(as.y + bs_.y + qs.y);
    unsigned int pk = (unsigned int)f2bf(m0) | ((unsigned int)f2bf(m1) << 16);
    unsigned int* addr = (unsigned int*)(hacc + (size_t)d * 128 + 2 * l);
    asm volatile("global_atomic_pk_add_bf16 %0, %1, off" :: "v"(addr), "v"(pk) : "memory");
}

// hb2 = relu(hb1) on bf16 (sign bit -> zero), 8 elems/thread
__global__ void relu_bf(const ushort_t* __restrict__ in, ushort_t* __restrict__ out, int n8) {
    int i = blockIdx.x * 256 + threadIdx.x;
    if (i >= n8) return;
    uint4 v = ((const uint4*)in)[i];
    unsigned int* pv = (unsigned int*)&v;
    #pragma unroll
    for (int j = 0; j < 4; ++j) {
        unsigned int u = pv[j];
        unsigned int lo = (u & 0x8000u) ? 0u : (u & 0xFFFFu);
        unsigned int hi = (u & 0x80000000u) ? 0u : (u & 0xFFFF0000u);
        pv[j] = lo | hi;
    }
    ((uint4*)out)[i] = v;
}

// out[n] = dot(hb[n,:], Wfc) + bfc ; one wave per node
__global__ __launch_bounds__(256) void final_fc(const ushort_t* __restrict__ hb,
                                                const float* __restrict__ W,
                                                const float* __restrict__ b,
                                                float* __restrict__ out) {
    int gid = blockIdx.x * 256 + threadIdx.x;
    int n = gid >> 6, lane = gid & 63;
    if (n >= NN) return;
    unsigned int hv = ((const unsigned int*)(hb + (size_t)n * 128))[lane];
    float2 h2 = upk(hv);
    float2 wv = ((const float2*)W)[lane];
    float p = h2.x * wv.x + h2.y * wv.y;
    #pragma unroll
    for (int off = 32; off > 0; off >>= 1) p += __shfl_down(p, off);
    if (lane == 0) out[n] = p + b[0];
}

extern "C" void kernel_launch(void* const* d_in, const int* in_sizes, int n_in,
                              void* d_out, int out_size, void* d_ws, size_t ws_size,
                              hipStream_t stream) {
    const float* x   = (const float*)d_in[0];
    const int*   ei  = (const int*)d_in[1];
    const float* ea  = (const float*)d_in[2];
    const float* Wf1 = (const float*)d_in[3];
    const float* bf1 = (const float*)d_in[4];
    const float* Ws1 = (const float*)d_in[5];
    const float* bs1 = (const float*)d_in[6];
    const float* Wf2 = (const float*)d_in[7];
    const float* bf2 = (const float*)d_in[8];
    const float* Ws2 = (const float*)d_in[9];
    const float* bs2 = (const float*)d_in[10];
    const float* Wfc = (const float*)d_in[11];
    const float* bfc = (const float*)d_in[12];
    float* out = (float*)d_out;

    ushort_t* hb1 = (ushort_t*)d_ws;                 // NN*128 bf16
    ushort_t* hb2 = hb1 + (size_t)NN * 128;          // NN*128 bf16
    ushort_t* P   = hb2 + (size_t)NN * 128;          // NN*512 bf16
    ushort_t* eab = P + (size_t)NN * 512;            // NE*64 bf16
    ushort_t* WT  = eab + (size_t)NE * 64;           // 2 x 512*128 bf16
    ushort_t* WeT = WT + 2 * 512 * 128;              // 2 x 256*64 bf16
    float* bcat   = (float*)(WeT + 2 * 256 * 64);    // 2 x 256 f32
    ushort_t* Qc  = (ushort_t*)(bcat + 512);         // CH*256 bf16

    size_t base_bytes = (size_t)((char*)Qc - (char*)d_ws);
    long availE = ((long)ws_size - (long)base_bytes) / 512;
    long CHl = availE < 131072 ? availE : 131072;
    if (CHl < 64) CHl = 64;
    int CH = (int)(CHl & ~63L);

    cvt_bf16<<<(NN * 128 / 8 + 255) / 256, 256, 0, stream>>>(x, hb1, NN * 128 / 8);
    cvt_bf16<<<(NE * 64 / 8 + 255) / 256, 256, 0, stream>>>(ea, eab, NE * 64 / 8);
    const int packN = 512 * 128 + 256 * 64 + 256;
    pack_weights<<<(packN + 255) / 256, 256, 0, stream>>>(Wf1, bf1, Ws1, bs1,
                                                          WT, WeT, bcat);
    pack_weights<<<(packN + 255) / 256, 256, 0, stream>>>(Wf2, bf2, Ws2, bs2,
                                                          WT + 512 * 128, WeT + 256 * 64, bcat + 256);

    for (int conv = 0; conv < 2; ++conv) {
        ushort_t* h = conv ? hb2 : hb1;   // GEMM input AND accumulation target
        node_gemm<<<dim3((NN + 63) / 64, 4), 256, 0, stream>>>(h, WT + conv * 512 * 128, P);
        for (int e0 = 0; e0 < NE; e0 += CH) {
            int ne = (NE - e0 < CH) ? (NE - e0) : CH;
            q_gemm<<<dim3((ne + 63) / 64, 2), 256, 0, stream>>>(
                eab, WeT + conv * 256 * 64, bcat + conv * 256, Qc, e0, ne);
            edge_kernel<<<((size_t)ne * 64 + 255) / 256, 256, 0, stream>>>(ei, P, Qc, h, e0, ne);
        }
        if (conv == 0) {
            relu_bf<<<(NN * 128 / 8 + 255) / 256, 256, 0, stream>>>(hb1, hb2, NN * 128 / 8);
        }
    }
    final_fc<<<((size_t)NN * 64 + 255) / 256, 256, 0, stream>>>(hb2, Wfc, bfc, out);
}

// Round 4
// 503.636 us; speedup vs baseline: 3.1534x; 1.2330x over previous
//
#include <hip/hip_runtime.h>
#include <math.h>

#define NN 50000
#define NE 400000

typedef __attribute__((ext_vector_type(8))) short bf16x8;
typedef __attribute__((ext_vector_type(4))) float f32x4;
typedef unsigned short ushort_t;

__device__ __forceinline__ unsigned short f2bf(float f) {
    unsigned int u = __float_as_uint(f);
    u += 0x7FFF + ((u >> 16) & 1);   // RNE
    return (unsigned short)(u >> 16);
}
__device__ __forceinline__ float2 upk(unsigned int w) {
    float2 r;
    r.x = __uint_as_float(w << 16);
    r.y = __uint_as_float(w & 0xFFFF0000u);
    return r;
}

#define LOG2E 1.4426950408889634f
#define LN2   0.6931471805599453f

// WT[512][128]: row c = output col, contiguous k. cols 0-127 Wf(dst), 128-255 Wf(src),
// 256-383 Ws(dst), 384-511 Ws(src). WeT[256][64] same idea for edge part. bcat=[bf|bs].
__global__ void pack_weights(const float* __restrict__ Wf, const float* __restrict__ bf,
                             const float* __restrict__ Ws, const float* __restrict__ bs,
                             ushort_t* __restrict__ WT, ushort_t* __restrict__ WeT,
                             float* __restrict__ bcat) {
    int i = blockIdx.x * 256 + threadIdx.x;
    if (i < 512 * 128) {
        int c = i >> 7, k = i & 127;
        float w;
        if (c < 128)      w = Wf[k * 128 + c];
        else if (c < 256) w = Wf[(128 + k) * 128 + (c - 128)];
        else if (c < 384) w = Ws[k * 128 + (c - 256)];
        else              w = Ws[(128 + k) * 128 + (c - 384)];
        WT[i] = f2bf(w);
    } else if (i < 512 * 128 + 256 * 64) {
        int j = i - 512 * 128;
        int c = j >> 6, k = j & 63;
        float w = (c < 128) ? Wf[(256 + k) * 128 + c] : Ws[(256 + k) * 128 + (c - 128)];
        WeT[j] = f2bf(w);
    } else if (i < 512 * 128 + 256 * 64 + 256) {
        int c = i - (512 * 128 + 256 * 64);
        bcat[c] = (c < 128) ? bf[c] : bs[c - 128];
    }
}

// fp32 -> bf16 bulk convert, 8 elems/thread
__global__ void cvt_bf16(const float* __restrict__ in, ushort_t* __restrict__ out, int n8) {
    int i = blockIdx.x * 256 + threadIdx.x;
    if (i >= n8) return;
    const float4* p = (const float4*)in + (size_t)i * 2;
    float4 a = p[0], b = p[1];
    bf16x8 v;
    v[0] = (short)f2bf(a.x); v[1] = (short)f2bf(a.y);
    v[2] = (short)f2bf(a.z); v[3] = (short)f2bf(a.w);
    v[4] = (short)f2bf(b.x); v[5] = (short)f2bf(b.y);
    v[6] = (short)f2bf(b.z); v[7] = (short)f2bf(b.w);
    *((bf16x8*)out + i) = v;
}

// P[NN][512] (bf16) = hb[NN][128] (bf16) @ W. Grid (ceil(NN/64), 4); 4 waves/block.
__global__ __launch_bounds__(256) void node_gemm(const ushort_t* __restrict__ hb,
                                                 const ushort_t* __restrict__ WT,
                                                 ushort_t* __restrict__ P) {
    __shared__ ushort_t Bs[128 * 136];
    const int tid = threadIdx.x;
    const int w = tid >> 6, l = tid & 63;
    const int by = blockIdx.y;
    const ushort_t* src = WT + (size_t)by * 128 * 128;
    #pragma unroll
    for (int j = 0; j < 8; ++j) {
        int cid = j * 256 + tid;            // 2048 chunks of 8 bf16
        int row = cid >> 4, off = (cid & 15) * 8;
        *(bf16x8*)(&Bs[row * 136 + off]) = *(const bf16x8*)(src + row * 128 + off);
    }
    __syncthreads();
    const int r0 = blockIdx.x * 64 + w * 16;
    const int lrow = l & 15, lk = l >> 4;
    int arow = r0 + lrow;
    if (arow >= NN) arow = NN - 1;
    f32x4 acc[8];
    #pragma unroll
    for (int i = 0; i < 8; ++i) acc[i] = (f32x4){0.f, 0.f, 0.f, 0.f};
    #pragma unroll
    for (int ks = 0; ks < 4; ++ks) {
        int kb = ks * 32 + lk * 8;
        bf16x8 af = *(const bf16x8*)(hb + (size_t)arow * 128 + kb);
        #pragma unroll
        for (int nc = 0; nc < 8; ++nc) {
            bf16x8 bfr = *(const bf16x8*)(&Bs[(nc * 16 + lrow) * 136 + kb]);
            acc[nc] = __builtin_amdgcn_mfma_f32_16x16x32_bf16(af, bfr, acc[nc], 0, 0, 0);
        }
    }
    const int rb = r0 + lk * 4;
    const int cb = by * 128;
    #pragma unroll
    for (int nc = 0; nc < 8; ++nc) {
        int col = cb + nc * 16 + lrow;
        #pragma unroll
        for (int r = 0; r < 4; ++r) {
            int row = rb + r;
            if (row < NN) P[(size_t)row * 512 + col] = f2bf(acc[nc][r]);
        }
    }
}

// Q[ne][256] (bf16) = eab[e0..][64] @ We + bcat. Grid (ceil(ne/64), 2).
__global__ __launch_bounds__(256) void q_gemm(const ushort_t* __restrict__ ea,
                                              const ushort_t* __restrict__ WeT,
                                              const float* __restrict__ bcat,
                                              ushort_t* __restrict__ Q,
                                              int e0, int ne) {
    __shared__ ushort_t Bs[128 * 72];
    const int tid = threadIdx.x;
    const int w = tid >> 6, l = tid & 63;
    const int by = blockIdx.y;
    const ushort_t* src = WeT + (size_t)by * 128 * 64;
    #pragma unroll
    for (int j = 0; j < 4; ++j) {
        int cid = j * 256 + tid;            // 1024 chunks of 8 bf16
        int row = cid >> 3, off = (cid & 7) * 8;
        *(bf16x8*)(&Bs[row * 72 + off]) = *(const bf16x8*)(src + row * 64 + off);
    }
    __syncthreads();
    const int r0 = blockIdx.x * 64 + w * 16;
    const int lrow = l & 15, lk = l >> 4;
    int arow = r0 + lrow;
    if (arow >= ne) arow = ne - 1;
    f32x4 acc[8];
    #pragma unroll
    for (int i = 0; i < 8; ++i) acc[i] = (f32x4){0.f, 0.f, 0.f, 0.f};
    #pragma unroll
    for (int ks = 0; ks < 2; ++ks) {
        int kb = ks * 32 + lk * 8;
        bf16x8 af = *(const bf16x8*)(ea + (size_t)(e0 + arow) * 64 + kb);
        #pragma unroll
        for (int nc = 0; nc < 8; ++nc) {
            bf16x8 bfr = *(const bf16x8*)(&Bs[(nc * 16 + lrow) * 72 + kb]);
            acc[nc] = __builtin_amdgcn_mfma_f32_16x16x32_bf16(af, bfr, acc[nc], 0, 0, 0);
        }
    }
    const int rb = r0 + lk * 4;
    const int cb = by * 128;
    #pragma unroll
    for (int nc = 0; nc < 8; ++nc) {
        int col = cb + nc * 16 + lrow;
        float bb = bcat[col];
        #pragma unroll
        for (int r = 0; r < 4; ++r) {
            int row = rb + r;
            if (row < ne) Q[(size_t)row * 256 + col] = f2bf(acc[nc][r] + bb);
        }
    }
}

// msg = sigmoid(gf)*softplus(gs) via raw v_exp_f32/v_log_f32/v_rcp_f32.
// Valid since |g| << 127: exp2 cannot overflow, both tails exact in fp32.
__device__ __forceinline__ float msg_act(float gf, float gs) {
    float tf = __builtin_amdgcn_exp2f(gf * -LOG2E);
    float sig = __builtin_amdgcn_rcpf(1.0f + tf) * LN2;   // sigmoid * ln2
    float ts = __builtin_amdgcn_exp2f(gs * LOG2E);
    float lg = __builtin_amdgcn_logf(1.0f + ts);          // log2(1+2^(s*log2e))
    return sig * lg;                                      // sigmoid(f)*softplus(s)
}

// One wave per edge; packed bf16 atomic accumulate into hb[dst] (in place, P already built).
__global__ __launch_bounds__(256) void edge_kernel(const int* __restrict__ ei,
                                                   const ushort_t* __restrict__ P,
                                                   const ushort_t* __restrict__ Q,
                                                   ushort_t* __restrict__ hacc,
                                                   int e0, int ne) {
    int gid = blockIdx.x * 256 + threadIdx.x;
    int wv = gid >> 6, l = gid & 63;
    if (wv >= ne) return;
    int e = e0 + wv;
    int s = ei[e];        // source (x_j)
    int d = ei[NE + e];   // target (x_i)
    const unsigned int* Pd = (const unsigned int*)(P + (size_t)d * 512);
    const unsigned int* Ps = (const unsigned int*)(P + (size_t)s * 512);
    const unsigned int* Qe = (const unsigned int*)(Q + (size_t)wv * 256);
    float2 af = upk(Pd[l]);
    float2 bf_ = upk(Ps[64 + l]);
    float2 as = upk(Pd[128 + l]);
    float2 bs_ = upk(Ps[192 + l]);
    float2 qf = upk(Qe[l]);
    float2 qs = upk(Qe[64 + l]);
    float m0 = msg_act(af.x + bf_.x + qf.x, as.x + bs_.x + qs.x);
    float m1 = msg_act(af.y + bf_.y + qf.y, as.y + bs_.y + qs.y);
    unsigned int pk = (unsigned int)f2bf(m0) | ((unsigned int)f2bf(m1) << 16);
    unsigned int* addr = (unsigned int*)(hacc + (size_t)d * 128 + 2 * l);
    asm volatile("global_atomic_pk_add_bf16 %0, %1, off" :: "v"(addr), "v"(pk) : "memory");
}

// hb2 = relu(hb1) on bf16 (sign bit -> zero), 8 elems/thread
__global__ void relu_bf(const ushort_t* __restrict__ in, ushort_t* __restrict__ out, int n8) {
    int i = blockIdx.x * 256 + threadIdx.x;
    if (i >= n8) return;
    uint4 v = ((const uint4*)in)[i];
    unsigned int* pv = (unsigned int*)&v;
    #pragma unroll
    for (int j = 0; j < 4; ++j) {
        unsigned int u = pv[j];
        unsigned int lo = (u & 0x8000u) ? 0u : (u & 0xFFFFu);
        unsigned int hi = (u & 0x80000000u) ? 0u : (u & 0xFFFF0000u);
        pv[j] = lo | hi;
    }
    ((uint4*)out)[i] = v;
}

// out[n] = dot(hb[n,:], Wfc) + bfc ; one wave per node
__global__ __launch_bounds__(256) void final_fc(const ushort_t* __restrict__ hb,
                                                const float* __restrict__ W,
                                                const float* __restrict__ b,
                                                float* __restrict__ out) {
    int gid = blockIdx.x * 256 + threadIdx.x;
    int n = gid >> 6, lane = gid & 63;
    if (n >= NN) return;
    unsigned int hv = ((const unsigned int*)(hb + (size_t)n * 128))[lane];
    float2 h2 = upk(hv);
    float2 wv = ((const float2*)W)[lane];
    float p = h2.x * wv.x + h2.y * wv.y;
    #pragma unroll
    for (int off = 32; off > 0; off >>= 1) p += __shfl_down(p, off);
    if (lane == 0) out[n] = p + b[0];
}

extern "C" void kernel_launch(void* const* d_in, const int* in_sizes, int n_in,
                              void* d_out, int out_size, void* d_ws, size_t ws_size,
                              hipStream_t stream) {
    const float* x   = (const float*)d_in[0];
    const int*   ei  = (const int*)d_in[1];
    const float* ea  = (const float*)d_in[2];
    const float* Wf1 = (const float*)d_in[3];
    const float* bf1 = (const float*)d_in[4];
    const float* Ws1 = (const float*)d_in[5];
    const float* bs1 = (const float*)d_in[6];
    const float* Wf2 = (const float*)d_in[7];
    const float* bf2 = (const float*)d_in[8];
    const float* Ws2 = (const float*)d_in[9];
    const float* bs2 = (const float*)d_in[10];
    const float* Wfc = (const float*)d_in[11];
    const float* bfc = (const float*)d_in[12];
    float* out = (float*)d_out;

    ushort_t* hb1 = (ushort_t*)d_ws;                 // NN*128 bf16
    ushort_t* hb2 = hb1 + (size_t)NN * 128;          // NN*128 bf16
    ushort_t* P   = hb2 + (size_t)NN * 128;          // NN*512 bf16
    ushort_t* eab = P + (size_t)NN * 512;            // NE*64 bf16
    ushort_t* WT  = eab + (size_t)NE * 64;           // 2 x 512*128 bf16
    ushort_t* WeT = WT + 2 * 512 * 128;              // 2 x 256*64 bf16
    float* bcat   = (float*)(WeT + 2 * 256 * 64);    // 2 x 256 f32
    ushort_t* Qc  = (ushort_t*)(bcat + 512);         // CH*256 bf16

    size_t base_bytes = (size_t)((char*)Qc - (char*)d_ws);
    long availE = ((long)ws_size - (long)base_bytes) / 512;
    long CHl = availE < 131072 ? availE : 131072;
    if (CHl < 64) CHl = 64;
    int CH = (int)(CHl & ~63L);

    cvt_bf16<<<(NN * 128 / 8 + 255) / 256, 256, 0, stream>>>(x, hb1, NN * 128 / 8);
    cvt_bf16<<<(NE * 64 / 8 + 255) / 256, 256, 0, stream>>>(ea, eab, NE * 64 / 8);
    const int packN = 512 * 128 + 256 * 64 + 256;
    pack_weights<<<(packN + 255) / 256, 256, 0, stream>>>(Wf1, bf1, Ws1, bs1,
                                                          WT, WeT, bcat);
    pack_weights<<<(packN + 255) / 256, 256, 0, stream>>>(Wf2, bf2, Ws2, bs2,
                                                          WT + 512 * 128, WeT + 256 * 64, bcat + 256);

    for (int conv = 0; conv < 2; ++conv) {
        ushort_t* h = conv ? hb2 : hb1;   // GEMM input AND accumulation target
        node_gemm<<<dim3((NN + 63) / 64, 4), 256, 0, stream>>>(h, WT + conv * 512 * 128, P);
        for (int e0 = 0; e0 < NE; e0 += CH) {
            int ne = (NE - e0 < CH) ? (NE - e0) : CH;
            q_gemm<<<dim3((ne + 63) / 64, 2), 256, 0, stream>>>(
                eab, WeT + conv * 256 * 64, bcat + conv * 256, Qc, e0, ne);
            edge_kernel<<<((size_t)ne * 64 + 255) / 256, 256, 0, stream>>>(ei, P, Qc, h, e0, ne);
        }
        if (conv == 0) {
            relu_bf<<<(NN * 128 / 8 + 255) / 256, 256, 0, stream>>>(hb1, hb2, NN * 128 / 8);
        }
    }
    final_fc<<<((size_t)NN * 64 + 255) / 256, 256, 0, stream>>>(hb2, Wfc, bfc, out);
}